// Round 5
// baseline (466.732 us; speedup 1.0000x reference)
//
#include <hip/hip_runtime.h>
#include <hip/hip_bf16.h>

// B=512, I=1152, K=8, L=16, O=7; IK=9216, LO=112.
// Round-4: TWO dispatches. prep0 + ONE fused routing kernel with hand-rolled
// cache-preserving barriers (cg::grid.sync costs ~45us because its
// system-scope acquire invalidates L2/L3 -> 58 MB HBM refetch, 99% idle).
// Design:
//   - Static operands (xbf, xT, wpT): normal cached loads, stay L2-hot
//     across all phases (never invalidated).
//   - Cross-phase data ONLY (vT 114KB, eb 72KB, Z 64B): agent-scope relaxed
//     atomic loads/stores (sc0/sc1, coherent at L3, bypass non-coherent L2).
//   - Barrier: atomicAdd arrive (after __syncthreads' vmcnt(0) drain) +
//     relaxed spin + s_sleep. No acquire fence -> no buffer_inv.
//   - bij lives in LDS (each g-block owns i=8*bid..+8 across iterations).
//   - Scaling back in-register (R0-proven numerics; R0 vs R1 showed its
//     VALU cost is invisible) -> wps buffer eliminated.
// 256 blocks x 512 thr, >=1 block/CU -> all co-resident -> spin is safe.
// Softmax deferred: fragments carry unnormalized exp, sq divides by Z_l.
// wpT pad rows (o==7) are exact zeros. Iter-3 bij update dead -> skipped.

#define NB 512
#define NI 1152
#define NLO 112
#define NIK 9216
#define NPAD 128             // padded N: n = l*8+o, o==7 is zero pad

typedef __attribute__((ext_vector_type(8))) short bf16x8;
typedef __attribute__((ext_vector_type(4))) float f32x4;

__device__ __forceinline__ ushort f2bf(float f) {
    __hip_bfloat16 h = __float2bfloat16(f);
    return *(ushort*)&h;
}
__device__ __forceinline__ float bf2f(short s) {
    union { unsigned int u; float f; } v;
    v.u = ((unsigned int)(unsigned short)s) << 16;
    return v.f;
}

// ---- agent-scope coherent access helpers (bypass non-coherent L2) ----
__device__ __forceinline__ float ld_cohf(const float* p) {
    return __hip_atomic_load((float*)p, __ATOMIC_RELAXED, __HIP_MEMORY_SCOPE_AGENT);
}
__device__ __forceinline__ void st_cohf(float* p, float v) {
    __hip_atomic_store(p, v, __ATOMIC_RELAXED, __HIP_MEMORY_SCOPE_AGENT);
}
__device__ __forceinline__ void st_cohu(ushort* p, ushort v) {
    __hip_atomic_store(p, v, __ATOMIC_RELAXED, __HIP_MEMORY_SCOPE_AGENT);
}
__device__ __forceinline__ bf16x8 ld_coh_frag(const ushort* p) {
    union { unsigned long long q[2]; bf16x8 v; } u;
    u.q[0] = __hip_atomic_load((unsigned long long*)p, __ATOMIC_RELAXED, __HIP_MEMORY_SCOPE_AGENT);
    u.q[1] = __hip_atomic_load((unsigned long long*)(p + 4), __ATOMIC_RELAXED, __HIP_MEMORY_SCOPE_AGENT);
    return u.v;
}

// ---- grid barrier, cache-preserving. All 256 blocks arrive. ----
__device__ __forceinline__ void gbar(int* ctr, int idx) {
    __syncthreads();   // compiler emits s_waitcnt vmcnt(0) before s_barrier:
                       // this block's coherent stores are complete at L3.
    if (threadIdx.x == 0) {
        asm volatile("s_waitcnt vmcnt(0)" ::: "memory");
        __hip_atomic_fetch_add(&ctr[idx], 1, __ATOMIC_RELAXED, __HIP_MEMORY_SCOPE_AGENT);
        while (__hip_atomic_load(&ctr[idx], __ATOMIC_RELAXED, __HIP_MEMORY_SCOPE_AGENT) < 256) {
            __builtin_amdgcn_s_sleep(2);
        }
    }
    __syncthreads();
    __builtin_amdgcn_sched_barrier(0);
}

// ---- conv_x body: x fp32 -> xbf [b][ik] and xT [ik][b], both bf16 ----
__device__ __forceinline__ void conv_x_body(const float* __restrict__ x,
                                            ushort* __restrict__ xbf,
                                            ushort* __restrict__ xT, int bid) {
    __shared__ ushort tile[64][68];
    int kg = bid % 144, bg = bid / 144;
    int k0 = kg * 64, b0 = bg * 64;
    int t = threadIdx.x;
    for (int e = t; e < 1024; e += 256) {
        int r = e >> 4, c4 = (e & 15) * 4;
        float4 f = *(const float4*)&x[(size_t)(b0 + r) * NIK + k0 + c4];
        ushort4 u = { f2bf(f.x), f2bf(f.y), f2bf(f.z), f2bf(f.w) };
        *(ushort4*)&xbf[(size_t)(b0 + r) * NIK + k0 + c4] = u;
        tile[r][c4] = u.x; tile[r][c4 + 1] = u.y; tile[r][c4 + 2] = u.z; tile[r][c4 + 3] = u.w;
    }
    __syncthreads();
    for (int e = t; e < 1024; e += 256) {
        int kr = e >> 4, c4 = (e & 15) * 4;
        ushort4 u = { tile[c4][kr], tile[c4 + 1][kr], tile[c4 + 2][kr], tile[c4 + 3][kr] };
        *(ushort4*)&xT[(size_t)(k0 + kr) * NB + b0 + c4] = u;
    }
}

// ---- prep0: conv_x (0..1151) + wpT build + eb0=1 + Z + barrier init ----
__global__ __launch_bounds__(256) void prep0(const float* __restrict__ x,
                                             ushort* __restrict__ xbf,
                                             ushort* __restrict__ xT,
                                             const float* __restrict__ w,
                                             ushort* __restrict__ wpT,
                                             float* __restrict__ eb,
                                             float* __restrict__ Z,
                                             int* __restrict__ bar) {
    if (blockIdx.x < 1152) { conv_x_body(x, xbf, xT, blockIdx.x); return; }
    __shared__ ushort tile[NPAD][66];
    int t = threadIdx.x;
    int wb = blockIdx.x - 1152;      // 0..143
    int ik0 = wb * 64;
    if (blockIdx.x == 1152) {
        if (t < 48) Z[t] = (t < 16) ? 1152.0f : 0.0f;
        if (t >= 48 && t < 64) bar[t - 48] = 0;
    }
    if (t < 128) eb[(size_t)(wb * 8 + (t >> 4)) * 16 + (t & 15)] = 1.0f;
    for (int e = t; e < 8192; e += 256) {
        int ikl = e >> 7, np = e & 127;
        int l = np >> 3, o = np & 7;
        float wv = (o < 7) ? w[(size_t)(ik0 + ikl) * NLO + l * 7 + o] : 0.f;
        tile[np][ikl] = f2bf(wv);
    }
    __syncthreads();
    for (int e = t; e < 8192; e += 256) {
        int np = e >> 6, ikl = e & 63;
        wpT[(size_t)np * NIK + ik0 + ikl] = tile[np][ikl];
    }
}

// ---- route2: fused 3-iteration routing loop, hand-rolled barriers ----
// sq geometry: block (mt=bid&31, ng=bid>>5) -> 16 b-rows x 16 n-cols,
//   8 waves K-split 9216/8=1152 (36 K-steps), in-register eb scaling,
//   6-deep ring prefetch. blocks sharing an xbf M-slice are bid%32-equal.
// g geometry: blocks 0..143, 8 waves = 4 ik-tiles x 2 B-halves (R0 form),
//   bij kept in LDS across iterations (block owns i=8*bid..+8).
__global__ __launch_bounds__(512, 2) void route2(const ushort* __restrict__ xbf,
                                                 const ushort* __restrict__ wpT,
                                                 float* __restrict__ eb,
                                                 float* __restrict__ Z,
                                                 ushort* __restrict__ vT,
                                                 float* __restrict__ out,
                                                 const ushort* __restrict__ xT,
                                                 const float* __restrict__ w,
                                                 int* __restrict__ bar) {
    __shared__ float csl[NI * 2];      // [i][lsel] 9.2 KB
    __shared__ float sp[8][16][16];    // [wave][m][n] 8 KB
    __shared__ float ss[16][16];
    __shared__ float facs[16][2];
    __shared__ float zi[2];
    __shared__ float bs[2][8][16];
    __shared__ float cs[128];
    __shared__ float bij_s[128];       // persists across iterations
    int bid = blockIdx.x;
    int t = threadIdx.x;
    int wv = t >> 6, lane = t & 63;
    int row = lane & 15, quad = lane >> 4;
    int mt = bid & 31, ng = bid >> 5;
    int b0 = mt * 16, n0 = ng * 16;
    int k0 = wv * 1152;                // 8-way K-split of 9216
    int lsel = row >> 3;
    int i0 = (k0 >> 3) + quad;         // i of this lane's fragment at ks=0
    const ushort* ap = xbf + (size_t)(b0 + row) * NIK + k0 + quad * 8;
    const ushort* bp = wpT + (size_t)(n0 + row) * NIK + k0 + quad * 8;

    for (int it = 0; it < 3; ++it) {
        // ---- stage this block's two l-columns of eb (coherent) + zi ----
        for (int e = t; e < NI * 2; e += 512) {
            int i = e >> 1, ls = e & 1;
            csl[e] = ld_cohf(&eb[(size_t)i * 16 + ng * 2 + ls]);
        }
        if (t < 2) zi[t] = 1.0f / ld_cohf(&Z[it * 16 + ng * 2 + t]);
        __syncthreads();
        // ---- sq GEMM: 6-deep ring prefetch, B scaled in-register ----
        bf16x8 ab[6], wb[6];
        #pragma unroll
        for (int p = 0; p < 6; ++p) {
            ab[p] = *(const bf16x8*)(ap + p * 32);
            wb[p] = *(const bf16x8*)(bp + p * 32);
        }
        f32x4 acc = {0.f, 0.f, 0.f, 0.f};
        #pragma unroll
        for (int ks = 0; ks < 36; ++ks) {  // 1152/32
            int s = ks % 6;
            float cv = csl[(i0 + ks * 4) * 2 + lsel];
            bf16x8 b;
            #pragma unroll
            for (int j = 0; j < 8; ++j) b[j] = (short)f2bf(bf2f(wb[s][j]) * cv);
            acc = __builtin_amdgcn_mfma_f32_16x16x32_bf16(ab[s], b, acc, 0, 0, 0);
            if (ks < 30) {
                ab[s] = *(const bf16x8*)(ap + (ks + 6) * 32);
                wb[s] = *(const bf16x8*)(bp + (ks + 6) * 32);
            }
        }
        #pragma unroll
        for (int r = 0; r < 4; ++r) sp[wv][quad * 4 + r][row] = acc[r];
        __syncthreads();
        if (t < 256) {
            int m = t >> 4, n = t & 15;
            float sv = 0.f;
            #pragma unroll
            for (int w8 = 0; w8 < 8; ++w8) sv += sp[w8][m][n];
            ss[m][n] = sv * zi[n >> 3];
        }
        __syncthreads();
        if (t < 32) {
            int m = t >> 1, ll = t & 1;
            float sq = 0.f;
            #pragma unroll
            for (int o = 0; o < 8; ++o) { float e = ss[m][ll * 8 + o]; sq += e * e; }
            facs[m][ll] = sqrtf(sq) / (1.0f + sq);   // == (sq/(1+sq))/norm
        }
        __syncthreads();
        if (t < 256) {
            int m = t >> 4, n = t & 15;
            int o = n & 7, lg = ng * 2 + (n >> 3);
            if (o < 7) {
                float vv = ss[m][n] * facs[m][n >> 3];
                st_cohu(&vT[(size_t)(o * 16 + lg) * NB + b0 + m], f2bf(vv));
                if (it == 2) out[(size_t)(b0 + m) * NLO + o * 16 + lg] = vv;
            }
        }
        if (it == 2) break;            // final v written; done
        gbar(bar, 2 * it);             // A(it): all vT visible

        // ---- g phase (blocks 0..143) ----
        if (bid < 144) {
            int half = wv & 1;
            int mtg = wv >> 1;               // 0..3
            int m0 = bid * 64 + mtg * 16;
            int kb0 = half * 256;
            const ushort* gap = xT + (size_t)(m0 + row) * NB + kb0 + quad * 8;
            const ushort* gbp = vT + (size_t)row * NB + kb0 + quad * 8;  // + nt*16*NB
            f32x4 gacc[7];
            #pragma unroll
            for (int nt = 0; nt < 7; ++nt) gacc[nt] = (f32x4){0.f, 0.f, 0.f, 0.f};
            for (int ks = 0; ks < 8; ++ks) {                 // 256/32
                bf16x8 a = *(const bf16x8*)(gap + ks * 32);
                #pragma unroll
                for (int nt = 0; nt < 7; ++nt) {
                    bf16x8 bfr = ld_coh_frag(gbp + (size_t)nt * 16 * NB + ks * 32);
                    gacc[nt] = __builtin_amdgcn_mfma_f32_16x16x32_bf16(a, bfr, gacc[nt], 0, 0, 0);
                }
            }
            // lane holds G[ik = m0+quad*4+r][o*16+l], o = nt, l = row
            float S = 0.f;
            #pragma unroll
            for (int r = 0; r < 4; ++r) {
                int ik = m0 + quad * 4 + r;
                const float* wr = w + (size_t)ik * NLO + row * 7;
                float p = 0.f;
                #pragma unroll
                for (int o = 0; o < 7; ++o) p += wr[o] * gacc[o][r];
                S += p;
            }
            float Sp = __shfl_down(S, 16);                   // partner quad's sum
            if ((quad & 1) == 0)
                bs[half][mtg * 2 + (quad >> 1)][row] = (S + Sp) * (1.0f / 512.0f);
            __syncthreads();
            if (t < 128) {
                float val = bs[0][t >> 4][t & 15] + bs[1][t >> 4][t & 15];
                if (it) val += bij_s[t];
                bij_s[t] = val;
                float e = expf(val);
                cs[t] = e;
                int i = bid * 8 + (t >> 4);
                st_cohf(&eb[(size_t)i * 16 + (t & 15)], e);
            }
            __syncthreads();
            if (t < 16) {
                float z = 0.f;
                #pragma unroll
                for (int j = 0; j < 8; ++j) z += cs[j * 16 + t];
                atomicAdd(&Z[(it + 1) * 16 + t], z);
            }
        }
        gbar(bar, 2 * it + 1);         // B(it): eb/Z visible
    }
}

extern "C" void kernel_launch(void* const* d_in, const int* in_sizes, int n_in,
                              void* d_out, int out_size, void* d_ws, size_t ws_size,
                              hipStream_t stream) {
    const float* x = (const float*)d_in[0];   // [512][9216]
    const float* w = (const float*)d_in[1];   // [9216][112]
    float* out = (float*)d_out;               // [512][112]
    float* ws = (float*)d_ws;
    float*  f_Z    = ws;                                  // 48
    int*    bar    = (int*)(ws + 48);                     // 16
    float*  f_eb   = ws + 64;                             // 18432
    ushort* xbf    = (ushort*)(f_eb + NI * 16);           // 512*9216
    ushort* xT     = xbf + (size_t)NB * NIK;              // 9216*512
    ushort* wpT    = xT + (size_t)NIK * NB;               // 128*9216
    ushort* vT     = wpT + (size_t)NPAD * NIK;            // 112*512
    prep0<<<1296, 256, 0, stream>>>(x, xbf, xT, w, wpT, f_eb, f_Z, bar);
    route2<<<256, 512, 0, stream>>>(xbf, wpT, f_eb, f_Z, vT, out, xT, w, bar);
}

// Round 6
// 276.333 us; speedup vs baseline: 1.6890x; 1.6890x over previous
//
#include <hip/hip_runtime.h>
#include <hip/hip_bf16.h>

// B=512, I=1152, K=8, L=16, O=7; IK=9216, LO=112.
// Round-5: TWO dispatches (160B memsetAsync + ONE fused kernel).
// All data accesses are NORMAL CACHED loads/stores. Cross-XCD visibility at
// phase boundaries comes from a hand-rolled grid barrier using agent-scope
// __threadfence() (L2 wb+inv only -- refetch hits the 256MB L3, never HBM;
// cg::grid.sync's system-scope fence was the 45us/sync killer in R2, and
// R4's cache-bypassing atomics were the 375us killer).
// Poison-fill stale-dirty-line hazard: barrier 0 (after prep) executes
// wbinv on EVERY XCD's L2 before any cross-phase data is produced, so no
// poison line can later be evicted over fresh L3 data.
// Phases: prep (x->xbf,xT; w->wpT) | 3x { sq | bar | g | bar }:
//   sq(it): s = xbf . (it? wps : wpT), 8-wave K-split, LDS reduce,
//           Z-divide + squash -> vT (+out on it==2).
//   g(it):  G = xT.vT MFMA -> w-contract -> bij (LDS-resident) -> cs=exp
//           -> Z atomicAdd + wps = bf16(cs * wpT) for next iter.
// Softmax deferred: wps carries unnormalized exp, sq divides by Z_l.
// wpT pad rows (o==7) are exact zeros. Iter-3 bij update dead -> skipped.
// 256 blocks x 512 thr, launch_bounds(512,2) -> <=128 VGPR -> every block
// resident (256 blocks on 256 CUs, capacity 2/CU) -> spin barrier is safe.

#define NB 512
#define NI 1152
#define NLO 112
#define NIK 9216
#define NPAD 128             // padded N: n = l*8+o, o==7 is zero pad

typedef __attribute__((ext_vector_type(8))) short bf16x8;
typedef __attribute__((ext_vector_type(4))) float f32x4;

__device__ __forceinline__ ushort f2bf(float f) {
    __hip_bfloat16 h = __float2bfloat16(f);
    return *(ushort*)&h;
}
__device__ __forceinline__ float bf2f(short s) {
    union { unsigned int u; float f; } v;
    v.u = ((unsigned int)(unsigned short)s) << 16;
    return v.f;
}

// ---- grid barrier: agent-scope fence (L2 wbinv, L3-backed), monotonic ctr ----
__device__ __forceinline__ void gbar(int* ctr, int target) {
    __syncthreads();                  // all block stores drained (vmcnt 0)
    if (threadIdx.x == 0) {
        __threadfence();              // agent acq_rel: wb+inv this XCD's L2
        __hip_atomic_fetch_add(ctr, 1, __ATOMIC_RELAXED, __HIP_MEMORY_SCOPE_AGENT);
        while (__hip_atomic_load(ctr, __ATOMIC_RELAXED, __HIP_MEMORY_SCOPE_AGENT) < target)
            __builtin_amdgcn_s_sleep(2);
        __threadfence();              // acquire: inv so post-barrier reads refetch
    }
    __syncthreads();
    __builtin_amdgcn_sched_barrier(0);
}

// ---- route_all: prep + full 3-iteration routing loop ----
__global__ __launch_bounds__(512, 2) void route_all(
        const float* __restrict__ x, const float* __restrict__ w,
        float* __restrict__ out,
        ushort* __restrict__ xbf, ushort* __restrict__ xT,
        ushort* __restrict__ wpT, ushort* __restrict__ wps,
        ushort* __restrict__ vT, float* __restrict__ Zbuf,
        int* __restrict__ bar) {
    __shared__ ushort tileA[64][68];   // 8.7 KB  (prep conv_x)
    __shared__ ushort tileW[NPAD][66]; // 16.9 KB (prep wpT build)
    __shared__ float sp[8][16][16];    // 8 KB    (sq K-split reduce)
    __shared__ float ss[16][16];
    __shared__ float facs[16][2];
    __shared__ float zi[2];
    __shared__ float bs[2][8][16];
    __shared__ float cs[128];
    __shared__ float bij_s[128];       // bij, persists across iterations
    const int bid = blockIdx.x;
    const int t = threadIdx.x;
    const int wv = t >> 6, lane = t & 63;
    const int row = lane & 15, quad = lane >> 4;

    // ---------------- prep phase (jobs strided over 256 blocks) ----------------
    for (int job = bid; job < 1296; job += 256) {
        if (job < 1152) {              // conv_x tile: x fp32 -> xbf + xT (bf16)
            int kg = job % 144, bg = job / 144;
            int k0 = kg * 64, b0 = bg * 64;
            for (int e = t; e < 1024; e += 512) {
                int r = e >> 4, c4 = (e & 15) * 4;
                float4 f = *(const float4*)&x[(size_t)(b0 + r) * NIK + k0 + c4];
                ushort4 u = { f2bf(f.x), f2bf(f.y), f2bf(f.z), f2bf(f.w) };
                *(ushort4*)&xbf[(size_t)(b0 + r) * NIK + k0 + c4] = u;
                tileA[r][c4] = u.x; tileA[r][c4 + 1] = u.y;
                tileA[r][c4 + 2] = u.z; tileA[r][c4 + 3] = u.w;
            }
            __syncthreads();
            for (int e = t; e < 1024; e += 512) {
                int kr = e >> 4, c4 = (e & 15) * 4;
                ushort4 u = { tileA[c4][kr], tileA[c4 + 1][kr],
                              tileA[c4 + 2][kr], tileA[c4 + 3][kr] };
                *(ushort4*)&xT[(size_t)(k0 + kr) * NB + b0 + c4] = u;
            }
            __syncthreads();
        } else {                       // wpT tile: w fp32 -> padded bf16 [np][ik]
            int wb = job - 1152;       // 0..143
            int ik0 = wb * 64;
            for (int e = t; e < 8192; e += 512) {
                int ikl = e >> 7, np = e & 127;
                int l = np >> 3, o = np & 7;
                float wf = (o < 7) ? w[(size_t)(ik0 + ikl) * NLO + l * 7 + o] : 0.f;
                tileW[np][ikl] = f2bf(wf);
            }
            __syncthreads();
            for (int e = t; e < 8192; e += 512) {
                int np = e >> 6, ikl = e & 63;
                wpT[(size_t)np * NIK + ik0 + ikl] = tileW[np][ikl];
            }
            __syncthreads();
        }
    }
    int barv = 256;
    gbar(bar, barv);                   // also flushes poison dirties everywhere

    // ---------------- routing loop ----------------
    const int mt = bid & 31, ng = bid >> 5;
    const int b0 = mt * 16, n0 = ng * 16;
    const int k0 = wv * 1152;          // 8-way K-split of 9216
    const ushort* ap = xbf + (size_t)(b0 + row) * NIK + k0 + quad * 8;

    for (int it = 0; it < 3; ++it) {
        // ---- sq phase ----
        if (t < 2) zi[t] = (it == 0) ? (1.0f / 1152.0f)
                                     : 1.0f / Zbuf[(it - 1) * 16 + ng * 2 + t];
        const ushort* bsrc = it ? wps : wpT;   // iter0 scale==1 -> wpT directly
        const ushort* bp = bsrc + (size_t)(n0 + row) * NIK + k0 + quad * 8;
        f32x4 acc = {0.f, 0.f, 0.f, 0.f};
        #pragma unroll 6
        for (int ks = 0; ks < 36; ++ks) {      // 1152/32
            bf16x8 a = *(const bf16x8*)(ap + ks * 32);
            bf16x8 b = *(const bf16x8*)(bp + ks * 32);
            acc = __builtin_amdgcn_mfma_f32_16x16x32_bf16(a, b, acc, 0, 0, 0);
        }
        #pragma unroll
        for (int r = 0; r < 4; ++r) sp[wv][quad * 4 + r][row] = acc[r];
        __syncthreads();
        if (t < 256) {
            int m = t >> 4, n = t & 15;
            float sv = 0.f;
            #pragma unroll
            for (int w8 = 0; w8 < 8; ++w8) sv += sp[w8][m][n];
            ss[m][n] = sv * zi[n >> 3];
        }
        __syncthreads();
        if (t < 32) {
            int m = t >> 1, ll = t & 1;
            float sq = 0.f;
            #pragma unroll
            for (int o = 0; o < 8; ++o) { float e = ss[m][ll * 8 + o]; sq += e * e; }
            facs[m][ll] = sqrtf(sq) / (1.0f + sq);   // == (sq/(1+sq))/norm
        }
        __syncthreads();
        if (t < 256) {
            int m = t >> 4, n = t & 15;
            int o = n & 7, lg = ng * 2 + (n >> 3);
            if (o < 7) {
                float vv = ss[m][n] * facs[m][n >> 3];
                vT[(size_t)(o * 16 + lg) * NB + b0 + m] = f2bf(vv);
                if (it == 2) out[(size_t)(b0 + m) * NLO + o * 16 + lg] = vv;
            }
        }
        if (it == 2) break;            // final v written; kernel-end flush
        barv += 256;
        gbar(bar, barv);               // vT visible grid-wide

        // ---- g phase (blocks 0..143; others fall through to barrier) ----
        if (bid < 144) {
            int half = wv & 1;
            int mtg = wv >> 1;               // 0..3 ik-tile
            int m0 = bid * 64 + mtg * 16;
            int kb0 = half * 256;
            const ushort* gap = xT + (size_t)(m0 + row) * NB + kb0 + quad * 8;
            const ushort* gbp = vT + (size_t)row * NB + kb0 + quad * 8;
            f32x4 gacc[7];
            #pragma unroll
            for (int nt = 0; nt < 7; ++nt) gacc[nt] = (f32x4){0.f, 0.f, 0.f, 0.f};
            for (int ks = 0; ks < 8; ++ks) {                 // 256/32
                bf16x8 a = *(const bf16x8*)(gap + ks * 32);
                #pragma unroll
                for (int nt = 0; nt < 7; ++nt) {
                    bf16x8 bfr = *(const bf16x8*)(gbp + (size_t)nt * 16 * NB + ks * 32);
                    gacc[nt] = __builtin_amdgcn_mfma_f32_16x16x32_bf16(a, bfr, gacc[nt], 0, 0, 0);
                }
            }
            // lane holds G[ik = m0+quad*4+r][o*16+l], o = nt, l = row
            float S = 0.f;
            #pragma unroll
            for (int r = 0; r < 4; ++r) {
                int ik = m0 + quad * 4 + r;
                const float* wr = w + (size_t)ik * NLO + row * 7;
                float p = 0.f;
                #pragma unroll
                for (int o = 0; o < 7; ++o) p += wr[o] * gacc[o][r];
                S += p;
            }
            float Sp = __shfl_down(S, 16);                   // partner quad's sum
            if ((quad & 1) == 0)
                bs[half][mtg * 2 + (quad >> 1)][row] = (S + Sp) * (1.0f / 512.0f);
            __syncthreads();
            if (t < 128) {
                float val = bs[0][t >> 4][t & 15] + bs[1][t >> 4][t & 15];
                if (it) val += bij_s[t];
                bij_s[t] = val;        // bij stays in LDS across iterations
                cs[t] = expf(val);     // cs[il*16 + l]
            }
            __syncthreads();
            if (t < 16) {
                float z = 0.f;
                #pragma unroll
                for (int j = 0; j < 8; ++j) z += cs[j * 16 + t];
                atomicAdd(&Zbuf[it * 16 + t], z);   // device-scope, coherent
            }
            // wps = bf16(cs * wpT) for next iter (block owns ik 64*bid..+63)
            int ik0 = bid * 64;
            for (int e = t; e < 2048; e += 512) {
                int np = e >> 4, i4 = (e & 15) * 4;
                float sc = cs[(i4 >> 3) * 16 + (np >> 3)];
                ushort4 wv4 = *(const ushort4*)&wpT[(size_t)np * NIK + ik0 + i4];
                ushort4 o4 = { f2bf(bf2f((short)wv4.x) * sc), f2bf(bf2f((short)wv4.y) * sc),
                               f2bf(bf2f((short)wv4.z) * sc), f2bf(bf2f((short)wv4.w) * sc) };
                *(ushort4*)&wps[(size_t)np * NIK + ik0 + i4] = o4;
            }
        }
        barv += 256;
        gbar(bar, barv);               // wps/Zbuf visible grid-wide
    }
}

extern "C" void kernel_launch(void* const* d_in, const int* in_sizes, int n_in,
                              void* d_out, int out_size, void* d_ws, size_t ws_size,
                              hipStream_t stream) {
    const float* x = (const float*)d_in[0];   // [512][9216]
    const float* w = (const float*)d_in[1];   // [9216][112]
    float* out = (float*)d_out;               // [512][112]
    float* ws = (float*)d_ws;
    float*  Zbuf = ws;                                    // 32 floats
    int*    bar  = (int*)(ws + 32);                       // 1 int (+pad)
    ushort* xbf  = (ushort*)(ws + 48);                    // 512*9216
    ushort* xT   = xbf + (size_t)NB * NIK;                // 9216*512
    ushort* wpT  = xT + (size_t)NIK * NB;                 // 128*9216 static
    ushort* wps  = wpT + (size_t)NPAD * NIK;              // 128*9216 scaled
    ushort* vT   = wps + (size_t)NPAD * NIK;              // 112*512
    hipMemsetAsync(ws, 0, 192, stream);                   // Zbuf + bar
    route_all<<<256, 512, 0, stream>>>(x, w, out, xbf, xT, wpT, wps, vT,
                                       Zbuf, bar);
}

// Round 7
// 207.093 us; speedup vs baseline: 2.2537x; 1.3343x over previous
//
#include <hip/hip_runtime.h>
#include <hip/hip_bf16.h>

// B=512, I=1152, K=8, L=16, O=7; IK=9216, LO=112.
// Round-6: fused kernel with FENCELESS iteration barriers.
// R5 lesson: __threadfence() at each barrier = full L2 wbinv on every XCD
// -> static operands refetched every phase (FETCH 69MB, 450 GB/s latency
// crawl, 217us). Fix: never invalidate. Cross-phase data is ping-ponged
// (vT0/vT1, wps0/wps1, Z padded per-iter) so consumers only ever read
// VIRGIN addresses (compulsory miss -> L3 -> fresh); producers write that
// data with agent-scope stores (bypass L2, land at L3 -- R4 proved both
// the bypass behavior and cross-XCD correctness of these stores).
// Hot-loop LOADS are all normal cached loads (R4's fatal mistake avoided).
// One fenced barrier remains (post-prep) to publish xbf/xT/wpT to L3;
// after that xbf/xT/wpT stay L2-hot across all 3 iterations.
// Phases: prep | FENCE-bar | 3x { sq | bar | g | bar } (fenceless bars):
//   sq(it): s = xbf . {wpT,wps0,wps1}[it], 8-wave K-split, LDS reduce,
//           Z-divide + squash -> vT[it] (WT) (+out on it==2).
//   g(it):  G = xT.vT[it] MFMA -> w-contract -> bij (LDS-resident) ->
//           cs=exp -> Z[it+1] atomicAdd + wps[it] = bf16(cs*wpT) (WT).
// Softmax deferred: wps carries unnormalized exp, sq divides by Z_l.
// wpT pad rows (o==7) are exact zeros. Iter-3 bij update dead -> skipped.
// 256 blocks x 512 thr = 1 block/CU, all resident -> spin barrier safe.

#define NB 512
#define NI 1152
#define NLO 112
#define NIK 9216
#define NPAD 128             // padded N: n = l*8+o, o==7 is zero pad

typedef __attribute__((ext_vector_type(8))) short bf16x8;
typedef __attribute__((ext_vector_type(4))) float f32x4;

__device__ __forceinline__ ushort f2bf(float f) {
    __hip_bfloat16 h = __float2bfloat16(f);
    return *(ushort*)&h;
}
__device__ __forceinline__ float bf2f(short s) {
    union { unsigned int u; float f; } v;
    v.u = ((unsigned int)(unsigned short)s) << 16;
    return v.f;
}

// agent-scope (L2-bypass, L3-coherent) helpers -- STAGING paths only
__device__ __forceinline__ void st_wt32(uint* p, uint v) {
    __hip_atomic_store(p, v, __ATOMIC_RELAXED, __HIP_MEMORY_SCOPE_AGENT);
}
__device__ __forceinline__ void st_wt64(unsigned long long* p, unsigned long long v) {
    __hip_atomic_store(p, v, __ATOMIC_RELAXED, __HIP_MEMORY_SCOPE_AGENT);
}
__device__ __forceinline__ float ld_cohf(const float* p) {
    return __hip_atomic_load((float*)p, __ATOMIC_RELAXED, __HIP_MEMORY_SCOPE_AGENT);
}

// fenced barrier (post-prep only): publishes normal stores to L3 via L2 wbinv
__device__ __forceinline__ void gbar_fence(int* ctr, int target) {
    __syncthreads();
    if (threadIdx.x == 0) {
        __threadfence();
        __hip_atomic_fetch_add(ctr, 1, __ATOMIC_RELAXED, __HIP_MEMORY_SCOPE_AGENT);
        while (__hip_atomic_load(ctr, __ATOMIC_RELAXED, __HIP_MEMORY_SCOPE_AGENT) < target)
            __builtin_amdgcn_s_sleep(2);
        __threadfence();
    }
    __syncthreads();
    __builtin_amdgcn_sched_barrier(0);
}

// fenceless barrier: producers' WT stores already at L3; consumers read
// virgin addresses only. Just drain + flag + spin.
__device__ __forceinline__ void gbar_fast(int* ctr, int target) {
    __syncthreads();                  // each wave drains its vmcnt before s_barrier
    if (threadIdx.x == 0) {
        asm volatile("s_waitcnt vmcnt(0)" ::: "memory");
        __hip_atomic_fetch_add(ctr, 1, __ATOMIC_RELAXED, __HIP_MEMORY_SCOPE_AGENT);
        while (__hip_atomic_load(ctr, __ATOMIC_RELAXED, __HIP_MEMORY_SCOPE_AGENT) < target)
            __builtin_amdgcn_s_sleep(2);
    }
    __syncthreads();
    __builtin_amdgcn_sched_barrier(0);
}

__global__ __launch_bounds__(512, 2) void route_all(
        const float* __restrict__ x, const float* __restrict__ w,
        float* __restrict__ out,
        ushort* __restrict__ xbf, ushort* __restrict__ xT,
        ushort* __restrict__ wpT,
        ushort* __restrict__ wps0, ushort* __restrict__ wps1,
        ushort* __restrict__ vT0, ushort* __restrict__ vT1,
        float* __restrict__ Zbuf, int* __restrict__ bar) {
    __shared__ ushort tileA[64][68];   // 8.7 KB  (prep conv_x)
    __shared__ ushort tileW[NPAD][66]; // 16.9 KB (prep wpT build)
    __shared__ float sp[8][16][16];    // 8 KB    (sq K-split reduce; sp[0] reused for v)
    __shared__ float ss[16][16];
    __shared__ float facs[16][2];
    __shared__ float zi[2];
    __shared__ float bs[2][8][16];
    __shared__ float cs[128];
    __shared__ float bij_s[128];       // bij, persists across iterations
    const int bid = blockIdx.x;
    const int t = threadIdx.x;
    const int wv = t >> 6, lane = t & 63;
    const int row = lane & 15, quad = lane >> 4;

    // ---------------- prep (jobs strided over 256 blocks) ----------------
    for (int job = bid; job < 1296; job += 256) {
        if (job < 1152) {              // conv_x: x fp32 -> xbf + xT (bf16)
            int kg = job % 144, bg = job / 144;
            int k0 = kg * 64, b0 = bg * 64;
            for (int e = t; e < 1024; e += 512) {
                int r = e >> 4, c4 = (e & 15) * 4;
                float4 f = *(const float4*)&x[(size_t)(b0 + r) * NIK + k0 + c4];
                ushort4 u = { f2bf(f.x), f2bf(f.y), f2bf(f.z), f2bf(f.w) };
                *(ushort4*)&xbf[(size_t)(b0 + r) * NIK + k0 + c4] = u;
                tileA[r][c4] = u.x; tileA[r][c4 + 1] = u.y;
                tileA[r][c4 + 2] = u.z; tileA[r][c4 + 3] = u.w;
            }
            __syncthreads();
            for (int e = t; e < 1024; e += 512) {
                int kr = e >> 4, c4 = (e & 15) * 4;
                ushort4 u = { tileA[c4][kr], tileA[c4 + 1][kr],
                              tileA[c4 + 2][kr], tileA[c4 + 3][kr] };
                *(ushort4*)&xT[(size_t)(k0 + kr) * NB + b0 + c4] = u;
            }
            __syncthreads();
        } else {                       // wpT: w fp32 -> padded bf16 [np][ik]
            int wb = job - 1152;       // 0..143
            int ik0 = wb * 64;
            for (int e = t; e < 8192; e += 512) {
                int ikl = e >> 7, np = e & 127;
                int l = np >> 3, o = np & 7;
                float wf = (o < 7) ? w[(size_t)(ik0 + ikl) * NLO + l * 7 + o] : 0.f;
                tileW[np][ikl] = f2bf(wf);
            }
            __syncthreads();
            for (int e = t; e < 8192; e += 512) {
                int np = e >> 6, ikl = e & 63;
                wpT[(size_t)np * NIK + ik0 + ikl] = tileW[np][ikl];
            }
            __syncthreads();
        }
    }
    int barv = 256;
    gbar_fence(bar, barv);             // publish xbf/xT/wpT; flush fill poison

    // ---------------- routing loop ----------------
    const int mt = bid & 31, ng = bid >> 5;
    const int b0 = mt * 16, n0 = ng * 16;
    const int k0 = wv * 1152;          // 8-way K-split of 9216
    const ushort* ap = xbf + (size_t)(b0 + row) * NIK + k0 + quad * 8;

    for (int it = 0; it < 3; ++it) {
        // ---- sq phase ----
        if (t < 2) zi[t] = (it == 0) ? (1.0f / 1152.0f)
                                     : 1.0f / ld_cohf(&Zbuf[it * 64 + ng * 2 + t]);
        const ushort* bsrc = (it == 0) ? wpT : ((it == 1) ? wps0 : wps1);
        const ushort* bp = bsrc + (size_t)(n0 + row) * NIK + k0 + quad * 8;
        f32x4 acc = {0.f, 0.f, 0.f, 0.f};
        #pragma unroll 6
        for (int ks = 0; ks < 36; ++ks) {      // 1152/32
            bf16x8 a = *(const bf16x8*)(ap + ks * 32);
            bf16x8 b = *(const bf16x8*)(bp + ks * 32);
            acc = __builtin_amdgcn_mfma_f32_16x16x32_bf16(a, b, acc, 0, 0, 0);
        }
        #pragma unroll
        for (int r = 0; r < 4; ++r) sp[wv][quad * 4 + r][row] = acc[r];
        __syncthreads();
        if (t < 256) {
            int m = t >> 4, n = t & 15;
            float sv = 0.f;
            #pragma unroll
            for (int w8 = 0; w8 < 8; ++w8) sv += sp[w8][m][n];
            ss[m][n] = sv * zi[n >> 3];
        }
        __syncthreads();
        if (t < 32) {
            int m = t >> 1, ll = t & 1;
            float sq = 0.f;
            #pragma unroll
            for (int o = 0; o < 8; ++o) { float e = ss[m][ll * 8 + o]; sq += e * e; }
            facs[m][ll] = sqrtf(sq) / (1.0f + sq);   // == (sq/(1+sq))/norm
        }
        __syncthreads();
        if (t < 256) {                 // v values -> sp[0] (sq reduce done)
            int m = t >> 4, n = t & 15;
            float vv = ss[m][n] * facs[m][n >> 3];
            sp[0][m][n] = vv;
            if (it == 2) {
                int o = n & 7, lg = ng * 2 + (n >> 3);
                if (o < 7) out[(size_t)(b0 + m) * NLO + o * 16 + lg] = vv;
            }
        }
        if (it == 2) break;            // final v written; kernel-end flush
        __syncthreads();
        if (t < 128) {                 // WT-pack vT[it]: 2 m's per uint
            int n = t >> 3, mp = t & 7;
            int o = n & 7, lg = ng * 2 + (n >> 3);
            if (o < 7) {
                uint lo = f2bf(sp[0][2 * mp][n]);
                uint hi = f2bf(sp[0][2 * mp + 1][n]);
                ushort* vTw = (it == 0) ? vT0 : vT1;
                st_wt32((uint*)(vTw + (size_t)(o * 16 + lg) * NB + b0 + 2 * mp),
                        lo | (hi << 16));
            }
        }
        barv += 256;
        gbar_fast(bar, barv);          // vT[it] at L3; consumers read virgin addrs

        // ---- g phase (blocks 0..143; others fall through to barrier) ----
        if (bid < 144) {
            const ushort* vTr = (it == 0) ? vT0 : vT1;
            int half = wv & 1;
            int mtg = wv >> 1;               // 0..3 ik-tile
            int m0 = bid * 64 + mtg * 16;
            int kb0 = half * 256;
            const ushort* gap = xT + (size_t)(m0 + row) * NB + kb0 + quad * 8;
            const ushort* gbp = vTr + (size_t)row * NB + kb0 + quad * 8;
            f32x4 gacc[7];
            #pragma unroll
            for (int nt = 0; nt < 7; ++nt) gacc[nt] = (f32x4){0.f, 0.f, 0.f, 0.f};
            for (int ks = 0; ks < 8; ++ks) {                 // 256/32
                bf16x8 a = *(const bf16x8*)(gap + ks * 32);
                #pragma unroll
                for (int nt = 0; nt < 7; ++nt) {
                    bf16x8 bfr = *(const bf16x8*)(gbp + (size_t)nt * 16 * NB + ks * 32);
                    gacc[nt] = __builtin_amdgcn_mfma_f32_16x16x32_bf16(a, bfr, gacc[nt], 0, 0, 0);
                }
            }
            // lane holds G[ik = m0+quad*4+r][o*16+l], o = nt, l = row
            float S = 0.f;
            #pragma unroll
            for (int r = 0; r < 4; ++r) {
                int ik = m0 + quad * 4 + r;
                const float* wr = w + (size_t)ik * NLO + row * 7;
                float p = 0.f;
                #pragma unroll
                for (int o = 0; o < 7; ++o) p += wr[o] * gacc[o][r];
                S += p;
            }
            float Sp = __shfl_down(S, 16);                   // partner quad's sum
            if ((quad & 1) == 0)
                bs[half][mtg * 2 + (quad >> 1)][row] = (S + Sp) * (1.0f / 512.0f);
            __syncthreads();
            if (t < 128) {
                float val = bs[0][t >> 4][t & 15] + bs[1][t >> 4][t & 15];
                if (it) val += bij_s[t];
                bij_s[t] = val;        // bij stays in LDS across iterations
                cs[t] = expf(val);     // cs[il*16 + l]
            }
            __syncthreads();
            if (t < 16) {
                float z = 0.f;
                #pragma unroll
                for (int j = 0; j < 8; ++j) z += cs[j * 16 + t];
                __hip_atomic_fetch_add(&Zbuf[(it + 1) * 64 + t], z,
                                       __ATOMIC_RELAXED, __HIP_MEMORY_SCOPE_AGENT);
            }
            // wps[it] = bf16(cs * wpT), WT (block owns ik 64*bid..+63)
            ushort* wpsw = (it == 0) ? wps0 : wps1;
            int ik0 = bid * 64;
            for (int e = t; e < 2048; e += 512) {
                int np = e >> 4, i4 = (e & 15) * 4;
                float sc = cs[(i4 >> 3) * 16 + (np >> 3)];
                ushort4 wv4 = *(const ushort4*)&wpT[(size_t)np * NIK + ik0 + i4];
                union { ushort4 s; unsigned long long q; } u;
                u.s = (ushort4){ f2bf(bf2f((short)wv4.x) * sc), f2bf(bf2f((short)wv4.y) * sc),
                                 f2bf(bf2f((short)wv4.z) * sc), f2bf(bf2f((short)wv4.w) * sc) };
                st_wt64((unsigned long long*)&wpsw[(size_t)np * NIK + ik0 + i4], u.q);
            }
        }
        barv += 256;
        gbar_fast(bar, barv);          // wps[it]/Z[it+1] at L3
    }
}

extern "C" void kernel_launch(void* const* d_in, const int* in_sizes, int n_in,
                              void* d_out, int out_size, void* d_ws, size_t ws_size,
                              hipStream_t stream) {
    const float* x = (const float*)d_in[0];   // [512][9216]
    const float* w = (const float*)d_in[1];   // [9216][112]
    float* out = (float*)d_out;               // [512][112]
    float* ws = (float*)d_ws;
    float*  Zbuf = ws;                                    // 3*64 floats, 256B/iter pad
    int*    bar  = (int*)(ws + 192);                      // own region
    ushort* xbf  = (ushort*)((char*)d_ws + 1024);         // 512*9216
    ushort* xT   = xbf + (size_t)NB * NIK;                // 9216*512
    ushort* wpT  = xT + (size_t)NIK * NB;                 // 128*9216 static
    ushort* wps0 = wpT + (size_t)NPAD * NIK;              // 128*9216 iter-1 B
    ushort* wps1 = wps0 + (size_t)NPAD * NIK;             // 128*9216 iter-2 B
    ushort* vT0  = wps1 + (size_t)NPAD * NIK;             // 112*512
    ushort* vT1  = vT0 + (size_t)NLO * NB;                // 112*512
    hipMemsetAsync(ws, 0, 1024, stream);                  // Zbuf + bar
    route_all<<<256, 512, 0, stream>>>(x, w, out, xbf, xT, wpT, wps0, wps1,
                                       vT0, vT1, Zbuf, bar);
}